// Round 7
// baseline (159.939 us; speedup 1.0000x reference)
//
#include <hip/hip_runtime.h>
#include <math.h>

#define IMH 512
#define IMW 512
#define RB    8     // output rows per wave-band (R5: halved -> 2x waves)
#define NBAND 64    // IMH / RB

typedef __attribute__((ext_vector_type(4))) float f32x4;

__device__ __forceinline__ int reflect_i(int v, int n) {
    if (v < 0) v = -v;
    if (v >= n) v = 2 * n - 2 - v;
    return v;
}
// branchless row reflect (valid for y in [-(IMH-1), 2*IMH-2])
__device__ __forceinline__ int reflect_row(int y) {
    int a = y < 0 ? -y : y;
    int b = 2 * IMH - 2 - a;
    return a < b ? a : b;
}
// DPP wave shifts (VALU pipe). 0x138=wave_shr1 (lane i <- i-1), 0x130=wave_shl1.
__device__ __forceinline__ float dpp_shr1(float x) {
    int i = __float_as_int(x);
    return __int_as_float(__builtin_amdgcn_update_dpp(i, i, 0x138, 0xF, 0xF, false));
}
__device__ __forceinline__ float dpp_shl1(float x) {
    int i = __float_as_int(x);
    return __int_as_float(__builtin_amdgcn_update_dpp(i, i, 0x130, 0xF, 0xF, false));
}

// ---------------- vec4 path: wave covers 256 cols, 4 px/lane -----------------
// R5 counters (57us, VALUBusy 11.8%, occ 7.1%, HBM 12%): latency-bound,
// occupancy-starved. vec4 raised per-wave BW 2.5x; restore wave count
// (RB=8 -> 3072 waves, 12/CU) and XCD swizzle for L2-hot halos.

struct V4S {
    float rr[4][4], gg[4][4], bb[4][4];   // depth-4 rolling load slots
    float h0[4], h1[4], h2[4], h3[4];     // hblur ring
    float b1[4], b0[4], b1L, b1R, b0L, b0R;   // vblur ring + lane-edge values
    float m1[4], m0[4], m1L, m1R, m0L, m0R;   // mag ring + lane-edge values
    float gxp[4], gyp[4];
};

__device__ __forceinline__ void vload(const float* __restrict__ p, int ro, int cx0,
                                      bool a0, float r[4]) {
    if (a0) {   // strip-A lane0: cols -4..-1 -> reflect -> 4,3,2,1
        r[0] = p[ro + 4]; r[1] = p[ro + 3]; r[2] = p[ro + 2]; r[3] = p[ro + 1];
    } else {
        f32x4 v = *reinterpret_cast<const f32x4*>(p + ro + cx0);
        r[0] = v.x; r[1] = v.y; r[2] = v.z; r[3] = v.w;
    }
}

template <int SL, bool DO_B, bool DO_M, bool DO_ST, bool REFILL>
__device__ __forceinline__ void vstep(V4S& S, int yL,
        const float* __restrict__ p0, const float* __restrict__ p1,
        const float* __restrict__ p2, float* __restrict__ outp,
        int cx0, bool a0, bool clampL, bool storeok) {
    const float w0 = 0.05448868f, w1 = 0.24420134f, w2 = 0.40261995f;
    float g[4];
    #pragma unroll
    for (int j = 0; j < 4; ++j)
        g[j] = 0.1495f * S.rr[SL][j] + 0.2935f * S.gg[SL][j] + 0.057f * S.bb[SL][j];
    if (REFILL) {   // refill slot 4 steps ahead
        int ro = reflect_row(yL + 4) * IMW;
        vload(p0, ro, cx0, a0, S.rr[SL]);
        vload(p1, ro, cx0, a0, S.gg[SL]);
        vload(p2, ro, cx0, a0, S.bb[SL]);
    }
    // cross-lane gray values for hblur (cols cx0-2, cx0-1, cx0+4, cx0+5)
    float Lm1 = dpp_shr1(g[3]), Lm2 = dpp_shr1(g[2]);
    float Rp1 = dpp_shl1(g[0]), Rp2 = dpp_shl1(g[1]);
    float hn[4];
    hn[0] = w0 * (Lm2 + g[2]) + w1 * (Lm1 + g[1]) + w2 * g[0];
    hn[1] = w0 * (Lm1 + g[3]) + w1 * (g[0] + g[2]) + w2 * g[1];
    hn[2] = w0 * (g[0] + Rp1) + w1 * (g[1] + g[3]) + w2 * g[2];
    hn[3] = w0 * (g[1] + Rp2) + w1 * (g[2] + Rp1) + w2 * g[3];

    float bn[4] = {0, 0, 0, 0};
    float bnL = 0, bnR = 0;
    if (DO_B) {
        #pragma unroll
        for (int j = 0; j < 4; ++j)
            bn[j] = w0 * (S.h0[j] + hn[j]) + w1 * (S.h1[j] + S.h3[j]) + w2 * S.h2[j];
        bnL = dpp_shr1(bn[3]); bnR = dpp_shl1(bn[0]);
    }
    float mn[4] = {0, 0, 0, 0}, gx[4] = {0, 0, 0, 0}, gy[4] = {0, 0, 0, 0};
    float mnL = 0, mnR = 0;
    if (DO_M) {
        const int u = yL - 3;
        float ta[4], tb[4], taL, taR, tbL, tbR;
        #pragma unroll
        for (int j = 0; j < 4; ++j) { ta[j] = S.b1[j]; tb[j] = bn[j]; }
        taL = S.b1L; taR = S.b1R; tbL = bnL; tbR = bnR;
        if (u == 0) {            // top edge (uniform branch, band 0 only)
            #pragma unroll
            for (int j = 0; j < 4; ++j) ta[j] = S.b0[j];
            taL = S.b0L; taR = S.b0R;
        }
        if (u == IMH - 1) {      // bottom edge (band NBAND-1 only)
            #pragma unroll
            for (int j = 0; j < 4; ++j) tb[j] = S.b0[j];
            tbL = S.b0L; tbR = S.b0R;
        }
        // sobel EDGE pad at image left: b(-1) := b(0)  (strip A, lane 1)
        if (clampL) { taL = ta[0]; tbL = tb[0]; }
        const float b0Ledge = clampL ? S.b0[0] : S.b0L;
        #pragma unroll
        for (int j = 0; j < 4; ++j) {
            float tla = (j == 0) ? taL : ta[j - 1];
            float tra = (j == 3) ? taR : ta[j + 1];
            float tlb = (j == 0) ? tbL : tb[j - 1];
            float trb = (j == 3) ? tbR : tb[j + 1];
            float bl0 = (j == 0) ? b0Ledge : S.b0[j - 1];
            float br0 = (j == 3) ? S.b0R : S.b0[j + 1];
            gx[j] = (tra - tla) + 2.0f * (br0 - bl0) + (trb - tlb);
            gy[j] = (tlb - tla) + 2.0f * (tb[j] - ta[j]) + (trb - tra);
            mn[j] = __builtin_amdgcn_sqrtf(gx[j] * gx[j] + gy[j] * gy[j] + 1e-6f);
        }
        // NMS ZERO pad at image left: mag(-1) := 0 (before edge DPPs)
        if (a0) mn[3] = 0.0f;
        mnL = dpp_shr1(mn[3]); mnR = dpp_shl1(mn[0]);
    }
    if (DO_ST) {
        const int s = yL - 4;
        float pm[4], nm[4], pmL, pmR, nmL, nmR;
        #pragma unroll
        for (int j = 0; j < 4; ++j) { pm[j] = S.m1[j]; nm[j] = mn[j]; }
        pmL = S.m1L; pmR = S.m1R; nmL = mnL; nmR = mnR;
        if (s == 0) {
            #pragma unroll
            for (int j = 0; j < 4; ++j) pm[j] = 0.0f;
            pmL = 0.0f; pmR = 0.0f;
        }
        if (s == IMH - 1) {
            #pragma unroll
            for (int j = 0; j < 4; ++j) nm[j] = 0.0f;
            nmL = 0.0f; nmR = 0.0f;
        }
        float o[4];
        #pragma unroll
        for (int j = 0; j < 4; ++j) {
            float pml = (j == 0) ? pmL : pm[j - 1];
            float pmr = (j == 3) ? pmR : pm[j + 1];
            float nml = (j == 0) ? nmL : nm[j - 1];
            float nmr = (j == 3) ? nmR : nm[j + 1];
            float ml0 = (j == 0) ? S.m0L : S.m0[j - 1];
            float mr0 = (j == 3) ? S.m0R : S.m0[j + 1];
            float ax = fabsf(S.gxp[j]), ay = fabsf(S.gyp[j]);
            bool ew = (ay <= 0.41421356237f * ax);
            bool ns = (ay >= 2.41421356237f * ax);
            bool d1 = (S.gxp[j] * S.gyp[j] > 0.0f);
            float n1 = ew ? mr0 : (ns ? nm[j] : (d1 ? pmr : nmr));
            float n2 = ew ? ml0 : (ns ? pm[j] : (d1 ? nml : pml));
            float mag = S.m0[j];
            o[j] = (mag > n1 && mag > n2) ? mag : 0.0f;
        }
        if (storeok) {
            f32x4 v; v.x = o[0]; v.y = o[1]; v.z = o[2]; v.w = o[3];
            __builtin_nontemporal_store(v,
                reinterpret_cast<f32x4*>(outp + (size_t)s * IMW + cx0));
        }
    }
    // ring shifts
    #pragma unroll
    for (int j = 0; j < 4; ++j) {
        S.h0[j] = S.h1[j]; S.h1[j] = S.h2[j]; S.h2[j] = S.h3[j]; S.h3[j] = hn[j];
        S.b1[j] = S.b0[j]; S.b0[j] = bn[j];
        S.m1[j] = S.m0[j]; S.m0[j] = mn[j];
        S.gxp[j] = gx[j];  S.gyp[j] = gy[j];
    }
    S.b1L = S.b0L; S.b1R = S.b0R; S.b0L = bnL; S.b0R = bnR;
    S.m1L = S.m0L; S.m1R = S.m0R; S.m0L = mnL; S.m0R = mnR;
}

__device__ __forceinline__ void run_band_v4(const float* __restrict__ p0,
                                            const float* __restrict__ p1,
                                            const float* __restrict__ p2,
                                            float* __restrict__ outp,
                                            int y0, int c0, int lane, bool isA) {
    const int cx0 = c0 + 4 * lane;
    const bool a0 = isA && (lane == 0);
    const bool clampL = isA && (lane == 1);   // owns col 0 -> sobel edge clamp
    // A out cols 0..247 = lanes 1..62; B out cols 248..491 = lanes 1..61
    const bool storeok = isA ? (lane >= 1 && lane <= 62) : (lane >= 1 && lane <= 61);
    V4S S;
    #pragma unroll
    for (int j = 0; j < 4; ++j) {
        S.h0[j] = S.h1[j] = S.h2[j] = S.h3[j] = 0.0f;
        S.b1[j] = S.b0[j] = 0.0f; S.m1[j] = S.m0[j] = 0.0f;
        S.gxp[j] = S.gyp[j] = 0.0f;
    }
    S.b1L = S.b1R = S.b0L = S.b0R = 0.0f;
    S.m1L = S.m1R = S.m0L = S.m0R = 0.0f;
    #pragma unroll
    for (int k = 0; k < 4; ++k) {
        int ro = reflect_row(y0 - 4 + k) * IMW;
        vload(p0, ro, cx0, a0, S.rr[k]);
        vload(p1, ro, cx0, a0, S.gg[k]);
        vload(p2, ro, cx0, a0, S.bb[k]);
    }
    // prologue peel k=0..7 (phase gates compile-time)
    vstep<0, false, false, false, true>(S, y0 - 4, p0, p1, p2, outp, cx0, a0, clampL, storeok);
    vstep<1, false, false, false, true>(S, y0 - 3, p0, p1, p2, outp, cx0, a0, clampL, storeok);
    vstep<2, false, false, false, true>(S, y0 - 2, p0, p1, p2, outp, cx0, a0, clampL, storeok);
    vstep<3, false, false, false, true>(S, y0 - 1, p0, p1, p2, outp, cx0, a0, clampL, storeok);
    vstep<0, true,  false, false, true>(S, y0 + 0, p0, p1, p2, outp, cx0, a0, clampL, storeok);
    vstep<1, true,  false, false, true>(S, y0 + 1, p0, p1, p2, outp, cx0, a0, clampL, storeok);
    vstep<2, true,  true,  false, true>(S, y0 + 2, p0, p1, p2, outp, cx0, a0, clampL, storeok);
    vstep<3, true,  true,  false, true>(S, y0 + 3, p0, p1, p2, outp, cx0, a0, clampL, storeok);
    // steady: k=8..RB+3, refill on (RB=8: one 4-step block)
    #pragma unroll 1
    for (int kb = 8; kb < RB + 4; kb += 4) {
        int yL = y0 - 4 + kb;
        vstep<0, true, true, true, true>(S, yL + 0, p0, p1, p2, outp, cx0, a0, clampL, storeok);
        vstep<1, true, true, true, true>(S, yL + 1, p0, p1, p2, outp, cx0, a0, clampL, storeok);
        vstep<2, true, true, true, true>(S, yL + 2, p0, p1, p2, outp, cx0, a0, clampL, storeok);
        vstep<3, true, true, true, true>(S, yL + 3, p0, p1, p2, outp, cx0, a0, clampL, storeok);
    }
    // tail: last 4 steps, no refill
    {
        int yL = y0 + RB;
        vstep<0, true, true, true, false>(S, yL + 0, p0, p1, p2, outp, cx0, a0, clampL, storeok);
        vstep<1, true, true, true, false>(S, yL + 1, p0, p1, p2, outp, cx0, a0, clampL, storeok);
        vstep<2, true, true, true, false>(S, yL + 2, p0, p1, p2, outp, cx0, a0, clampL, storeok);
        vstep<3, true, true, true, false>(S, yL + 3, p0, p1, p2, outp, cx0, a0, clampL, storeok);
    }
}

// ---------------- scalar path (strip C only: right edge, 64 cols) ------------
__device__ __forceinline__ void run_band_sc(const float* __restrict__ p0,
                                            const float* __restrict__ p1,
                                            const float* __restrict__ p2,
                                            float* __restrict__ outp,
                                            int y0, int c0, int lane) {
    const float w0 = 0.05448868f, w1 = 0.24420134f, w2 = 0.40261995f;
    const int cx = c0 + lane;
    const int rx = reflect_i(cx, IMW);
    const int ixm = ((cx - 1 < 0) ? 0 : (cx - 1 >= IMW ? IMW - 1 : cx - 1)) - c0;
    const int ixp = ((cx + 1 < 0) ? 0 : (cx + 1 >= IMW ? IMW - 1 : cx + 1)) - c0;
    const bool storeok = (lane >= 4) && (lane < 60) && ((unsigned)cx < (unsigned)IMW);

    float h0 = 0, h1 = 0, h2 = 0, h3 = 0;
    float b_1 = 0, b_0 = 0, bl_1 = 0, bl_0 = 0, br_1 = 0, br_0 = 0;
    float m_1 = 0, m_0 = 0, ml_1 = 0, ml_0 = 0, mr_1 = 0, mr_0 = 0;
    float gxp = 0, gyp = 0;

    float rr[4], gg[4], bb[4];
    #pragma unroll
    for (int k = 0; k < 4; ++k) {
        int yo = reflect_row(y0 - 4 + k) * IMW + rx;
        rr[k] = p0[yo]; gg[k] = p1[yo]; bb[k] = p2[yo];
    }

    #pragma unroll
    for (int k = 0; k < RB + 8; ++k) {
        const int yL = y0 - 4 + k;
        const int sl = k & 3;
        float gray = 0.1495f * rr[sl] + 0.2935f * gg[sl] + 0.057f * bb[sl];
        if (k + 4 < RB + 8) {
            int yo = reflect_row(yL + 4) * IMW + rx;
            rr[sl] = p0[yo]; gg[sl] = p1[yo]; bb[sl] = p2[yo];
        }
        float gm1 = dpp_shr1(gray);
        float gm2 = dpp_shr1(gm1);
        float gp1 = dpp_shl1(gray);
        float gp2 = dpp_shl1(gp1);
        float hnew = w0 * (gm2 + gp2) + w1 * (gm1 + gp1) + w2 * gray;

        float bnew = 0, blnew = 0, brnew = 0;
        if (k >= 4) {
            bnew = w0 * (h0 + hnew) + w1 * (h1 + h3) + w2 * h2;
            blnew = __shfl(bnew, ixm); brnew = __shfl(bnew, ixp);
        }

        float mnew = 0, mlnew = 0, mrnew = 0, gx = 0, gy = 0;
        if (k >= 6) {
            int u = yL - 3;
            float ta = b_1, tla = bl_1, tra = br_1;
            float tb = bnew, tlb = blnew, trb = brnew;
            if (u == 0)       { ta = b_0; tla = bl_0; tra = br_0; }
            if (u == IMH - 1) { tb = b_0; tlb = bl_0; trb = br_0; }
            gx = (tra - tla) + 2.0f * (br_0 - bl_0) + (trb - tlb);
            gy = (tlb - tla) + 2.0f * (tb - ta) + (trb - tra);
            mnew = __builtin_amdgcn_sqrtf(gx * gx + gy * gy + 1e-6f);
            if ((unsigned)cx >= (unsigned)IMW) mnew = 0.0f;
            mlnew = dpp_shr1(mnew);
            mrnew = dpp_shl1(mnew);
        }

        if (k >= 8) {
            int s = yL - 4;
            float pm = m_1, pml = ml_1, pmr = mr_1;
            float nm = mnew, nml = mlnew, nmr = mrnew;
            if (s == 0)       { pm = 0; pml = 0; pmr = 0; }
            if (s == IMH - 1) { nm = 0; nml = 0; nmr = 0; }
            float ax = fabsf(gxp), ay = fabsf(gyp);
            bool ew = (ay <= 0.41421356237f * ax);
            bool ns = (ay >= 2.41421356237f * ax);
            bool d1 = (gxp * gyp > 0.0f);
            float n1 = ew ? mr_0 : (ns ? nm : (d1 ? pmr : nmr));
            float n2 = ew ? ml_0 : (ns ? pm : (d1 ? nml : pml));
            float mag = m_0;
            float o = (mag > n1 && mag > n2) ? mag : 0.0f;
            if (storeok)
                __builtin_nontemporal_store(o, &outp[(size_t)s * IMW + cx]);
        }

        h0 = h1; h1 = h2; h2 = h3; h3 = hnew;
        b_1 = b_0;  b_0 = bnew;
        bl_1 = bl_0; bl_0 = blnew;
        br_1 = br_0; br_0 = brnew;
        m_1 = m_0;  m_0 = mnew;
        ml_1 = ml_0; ml_0 = mlnew;
        mr_1 = mr_0; mr_0 = mrnew;
        gxp = gx; gyp = gy;
    }
}

__global__ __launch_bounds__(256, 4)
void canny_stream(const float* __restrict__ data, float* __restrict__ out) {
    const int lane = threadIdx.x & 63;
    // R5: XCD-aware swizzle restored. blocks with equal blockIdx%8 -> one XCD;
    // each XCD owns 2 batches (6MB) walked band-sequentially for L2 halo hits.
    // waves: (bat) x (band 0..63) x (strip 0..2); 3072 waves = 768 blocks.
    const int xcd = blockIdx.x & 7;
    const int seq = blockIdx.x >> 3;               // 0..95
    const int lw  = seq * 4 + (threadIdx.x >> 6);  // 0..383 within XCD
    const int strip = lw % 3;
    const int t = lw / 3;                          // 0..127
    const int band = t & (NBAND - 1);
    const int bat = (xcd << 1) | (t >> 6);
    const int y0 = band * RB;

    const size_t plane = (size_t)(IMH * IMW);
    const float* p0 = data + (size_t)bat * 3 * plane;
    const float* p1 = p0 + plane;
    const float* p2 = p1 + plane;
    float* outp = out + (size_t)bat * plane;

    if (strip == 2) {
        run_band_sc(p0, p1, p2, outp, y0, 488, lane);          // out 492..511
    } else if (strip == 0) {
        run_band_v4(p0, p1, p2, outp, y0, -4, lane, true);     // out 0..247
    } else {
        run_band_v4(p0, p1, p2, outp, y0, 244, lane, false);   // out 248..491
    }
}

extern "C" void kernel_launch(void* const* d_in, const int* in_sizes, int n_in,
                              void* d_out, int out_size, void* d_ws, size_t ws_size,
                              hipStream_t stream) {
    const float* data = (const float*)d_in[0];
    float* out = (float*)d_out;
    int B = in_sizes[0] / (3 * IMH * IMW);       // 16
    int blocks = (B * NBAND * 3) / 4;            // 768 blocks, 3072 waves
    canny_stream<<<blocks, dim3(256, 1, 1), 0, stream>>>(data, out);
}

// Round 8
// 104.700 us; speedup vs baseline: 1.5276x; 1.5276x over previous
//
#include <hip/hip_runtime.h>
#include <math.h>

#define IMH 512
#define IMW 512
#define RB    8     // output rows per wave-band (R5: halved -> 2x waves)
#define NBAND 64    // IMH / RB

typedef __attribute__((ext_vector_type(4))) float f32x4;

__device__ __forceinline__ int reflect_i(int v, int n) {
    if (v < 0) v = -v;
    if (v >= n) v = 2 * n - 2 - v;
    return v;
}
// branchless row reflect (valid for y in [-(IMH-1), 2*IMH-2])
__device__ __forceinline__ int reflect_row(int y) {
    int a = y < 0 ? -y : y;
    int b = 2 * IMH - 2 - a;
    return a < b ? a : b;
}
// DPP wave shifts (VALU pipe). 0x138=wave_shr1 (lane i <- i-1), 0x130=wave_shl1.
__device__ __forceinline__ float dpp_shr1(float x) {
    int i = __float_as_int(x);
    return __int_as_float(__builtin_amdgcn_update_dpp(i, i, 0x138, 0xF, 0xF, false));
}
__device__ __forceinline__ float dpp_shl1(float x) {
    int i = __float_as_int(x);
    return __int_as_float(__builtin_amdgcn_update_dpp(i, i, 0x130, 0xF, 0xF, false));
}

// ---------------- vec4 path: wave covers 256 cols, 4 px/lane -----------------
// R7 post-mortem: __launch_bounds__(256,4) forced VGPR 100->64 -> ~61MB scratch
// spill per dispatch (WRITE_SIZE 17->78MB), kernel 57->90us. R8: revert to
// (256,2) (R5-proven: VGPR=100, no spill). At 100 VGPR HW allows 4 waves/SIMD,
// so the RB=8 grid (12 waves/CU, 3 blocks/CU, 768 blocks) stays fully resident.

struct V4S {
    float rr[4][4], gg[4][4], bb[4][4];   // depth-4 rolling load slots
    float h0[4], h1[4], h2[4], h3[4];     // hblur ring
    float b1[4], b0[4], b1L, b1R, b0L, b0R;   // vblur ring + lane-edge values
    float m1[4], m0[4], m1L, m1R, m0L, m0R;   // mag ring + lane-edge values
    float gxp[4], gyp[4];
};

__device__ __forceinline__ void vload(const float* __restrict__ p, int ro, int cx0,
                                      bool a0, float r[4]) {
    if (a0) {   // strip-A lane0: cols -4..-1 -> reflect -> 4,3,2,1
        r[0] = p[ro + 4]; r[1] = p[ro + 3]; r[2] = p[ro + 2]; r[3] = p[ro + 1];
    } else {
        f32x4 v = *reinterpret_cast<const f32x4*>(p + ro + cx0);
        r[0] = v.x; r[1] = v.y; r[2] = v.z; r[3] = v.w;
    }
}

template <int SL, bool DO_B, bool DO_M, bool DO_ST, bool REFILL>
__device__ __forceinline__ void vstep(V4S& S, int yL,
        const float* __restrict__ p0, const float* __restrict__ p1,
        const float* __restrict__ p2, float* __restrict__ outp,
        int cx0, bool a0, bool clampL, bool storeok) {
    const float w0 = 0.05448868f, w1 = 0.24420134f, w2 = 0.40261995f;
    float g[4];
    #pragma unroll
    for (int j = 0; j < 4; ++j)
        g[j] = 0.1495f * S.rr[SL][j] + 0.2935f * S.gg[SL][j] + 0.057f * S.bb[SL][j];
    if (REFILL) {   // refill slot 4 steps ahead
        int ro = reflect_row(yL + 4) * IMW;
        vload(p0, ro, cx0, a0, S.rr[SL]);
        vload(p1, ro, cx0, a0, S.gg[SL]);
        vload(p2, ro, cx0, a0, S.bb[SL]);
    }
    // cross-lane gray values for hblur (cols cx0-2, cx0-1, cx0+4, cx0+5)
    float Lm1 = dpp_shr1(g[3]), Lm2 = dpp_shr1(g[2]);
    float Rp1 = dpp_shl1(g[0]), Rp2 = dpp_shl1(g[1]);
    float hn[4];
    hn[0] = w0 * (Lm2 + g[2]) + w1 * (Lm1 + g[1]) + w2 * g[0];
    hn[1] = w0 * (Lm1 + g[3]) + w1 * (g[0] + g[2]) + w2 * g[1];
    hn[2] = w0 * (g[0] + Rp1) + w1 * (g[1] + g[3]) + w2 * g[2];
    hn[3] = w0 * (g[1] + Rp2) + w1 * (g[2] + Rp1) + w2 * g[3];

    float bn[4] = {0, 0, 0, 0};
    float bnL = 0, bnR = 0;
    if (DO_B) {
        #pragma unroll
        for (int j = 0; j < 4; ++j)
            bn[j] = w0 * (S.h0[j] + hn[j]) + w1 * (S.h1[j] + S.h3[j]) + w2 * S.h2[j];
        bnL = dpp_shr1(bn[3]); bnR = dpp_shl1(bn[0]);
    }
    float mn[4] = {0, 0, 0, 0}, gx[4] = {0, 0, 0, 0}, gy[4] = {0, 0, 0, 0};
    float mnL = 0, mnR = 0;
    if (DO_M) {
        const int u = yL - 3;
        float ta[4], tb[4], taL, taR, tbL, tbR;
        #pragma unroll
        for (int j = 0; j < 4; ++j) { ta[j] = S.b1[j]; tb[j] = bn[j]; }
        taL = S.b1L; taR = S.b1R; tbL = bnL; tbR = bnR;
        if (u == 0) {            // top edge (uniform branch, band 0 only)
            #pragma unroll
            for (int j = 0; j < 4; ++j) ta[j] = S.b0[j];
            taL = S.b0L; taR = S.b0R;
        }
        if (u == IMH - 1) {      // bottom edge (band NBAND-1 only)
            #pragma unroll
            for (int j = 0; j < 4; ++j) tb[j] = S.b0[j];
            tbL = S.b0L; tbR = S.b0R;
        }
        // sobel EDGE pad at image left: b(-1) := b(0)  (strip A, lane 1)
        if (clampL) { taL = ta[0]; tbL = tb[0]; }
        const float b0Ledge = clampL ? S.b0[0] : S.b0L;
        #pragma unroll
        for (int j = 0; j < 4; ++j) {
            float tla = (j == 0) ? taL : ta[j - 1];
            float tra = (j == 3) ? taR : ta[j + 1];
            float tlb = (j == 0) ? tbL : tb[j - 1];
            float trb = (j == 3) ? tbR : tb[j + 1];
            float bl0 = (j == 0) ? b0Ledge : S.b0[j - 1];
            float br0 = (j == 3) ? S.b0R : S.b0[j + 1];
            gx[j] = (tra - tla) + 2.0f * (br0 - bl0) + (trb - tlb);
            gy[j] = (tlb - tla) + 2.0f * (tb[j] - ta[j]) + (trb - tra);
            mn[j] = __builtin_amdgcn_sqrtf(gx[j] * gx[j] + gy[j] * gy[j] + 1e-6f);
        }
        // NMS ZERO pad at image left: mag(-1) := 0 (before edge DPPs)
        if (a0) mn[3] = 0.0f;
        mnL = dpp_shr1(mn[3]); mnR = dpp_shl1(mn[0]);
    }
    if (DO_ST) {
        const int s = yL - 4;
        float pm[4], nm[4], pmL, pmR, nmL, nmR;
        #pragma unroll
        for (int j = 0; j < 4; ++j) { pm[j] = S.m1[j]; nm[j] = mn[j]; }
        pmL = S.m1L; pmR = S.m1R; nmL = mnL; nmR = mnR;
        if (s == 0) {
            #pragma unroll
            for (int j = 0; j < 4; ++j) pm[j] = 0.0f;
            pmL = 0.0f; pmR = 0.0f;
        }
        if (s == IMH - 1) {
            #pragma unroll
            for (int j = 0; j < 4; ++j) nm[j] = 0.0f;
            nmL = 0.0f; nmR = 0.0f;
        }
        float o[4];
        #pragma unroll
        for (int j = 0; j < 4; ++j) {
            float pml = (j == 0) ? pmL : pm[j - 1];
            float pmr = (j == 3) ? pmR : pm[j + 1];
            float nml = (j == 0) ? nmL : nm[j - 1];
            float nmr = (j == 3) ? nmR : nm[j + 1];
            float ml0 = (j == 0) ? S.m0L : S.m0[j - 1];
            float mr0 = (j == 3) ? S.m0R : S.m0[j + 1];
            float ax = fabsf(S.gxp[j]), ay = fabsf(S.gyp[j]);
            bool ew = (ay <= 0.41421356237f * ax);
            bool ns = (ay >= 2.41421356237f * ax);
            bool d1 = (S.gxp[j] * S.gyp[j] > 0.0f);
            float n1 = ew ? mr0 : (ns ? nm[j] : (d1 ? pmr : nmr));
            float n2 = ew ? ml0 : (ns ? pm[j] : (d1 ? nml : pml));
            float mag = S.m0[j];
            o[j] = (mag > n1 && mag > n2) ? mag : 0.0f;
        }
        if (storeok) {
            f32x4 v; v.x = o[0]; v.y = o[1]; v.z = o[2]; v.w = o[3];
            __builtin_nontemporal_store(v,
                reinterpret_cast<f32x4*>(outp + (size_t)s * IMW + cx0));
        }
    }
    // ring shifts
    #pragma unroll
    for (int j = 0; j < 4; ++j) {
        S.h0[j] = S.h1[j]; S.h1[j] = S.h2[j]; S.h2[j] = S.h3[j]; S.h3[j] = hn[j];
        S.b1[j] = S.b0[j]; S.b0[j] = bn[j];
        S.m1[j] = S.m0[j]; S.m0[j] = mn[j];
        S.gxp[j] = gx[j];  S.gyp[j] = gy[j];
    }
    S.b1L = S.b0L; S.b1R = S.b0R; S.b0L = bnL; S.b0R = bnR;
    S.m1L = S.m0L; S.m1R = S.m0R; S.m0L = mnL; S.m0R = mnR;
}

__device__ __forceinline__ void run_band_v4(const float* __restrict__ p0,
                                            const float* __restrict__ p1,
                                            const float* __restrict__ p2,
                                            float* __restrict__ outp,
                                            int y0, int c0, int lane, bool isA) {
    const int cx0 = c0 + 4 * lane;
    const bool a0 = isA && (lane == 0);
    const bool clampL = isA && (lane == 1);   // owns col 0 -> sobel edge clamp
    // A out cols 0..247 = lanes 1..62; B out cols 248..491 = lanes 1..61
    const bool storeok = isA ? (lane >= 1 && lane <= 62) : (lane >= 1 && lane <= 61);
    V4S S;
    #pragma unroll
    for (int j = 0; j < 4; ++j) {
        S.h0[j] = S.h1[j] = S.h2[j] = S.h3[j] = 0.0f;
        S.b1[j] = S.b0[j] = 0.0f; S.m1[j] = S.m0[j] = 0.0f;
        S.gxp[j] = S.gyp[j] = 0.0f;
    }
    S.b1L = S.b1R = S.b0L = S.b0R = 0.0f;
    S.m1L = S.m1R = S.m0L = S.m0R = 0.0f;
    #pragma unroll
    for (int k = 0; k < 4; ++k) {
        int ro = reflect_row(y0 - 4 + k) * IMW;
        vload(p0, ro, cx0, a0, S.rr[k]);
        vload(p1, ro, cx0, a0, S.gg[k]);
        vload(p2, ro, cx0, a0, S.bb[k]);
    }
    // prologue peel k=0..7 (phase gates compile-time)
    vstep<0, false, false, false, true>(S, y0 - 4, p0, p1, p2, outp, cx0, a0, clampL, storeok);
    vstep<1, false, false, false, true>(S, y0 - 3, p0, p1, p2, outp, cx0, a0, clampL, storeok);
    vstep<2, false, false, false, true>(S, y0 - 2, p0, p1, p2, outp, cx0, a0, clampL, storeok);
    vstep<3, false, false, false, true>(S, y0 - 1, p0, p1, p2, outp, cx0, a0, clampL, storeok);
    vstep<0, true,  false, false, true>(S, y0 + 0, p0, p1, p2, outp, cx0, a0, clampL, storeok);
    vstep<1, true,  false, false, true>(S, y0 + 1, p0, p1, p2, outp, cx0, a0, clampL, storeok);
    vstep<2, true,  true,  false, true>(S, y0 + 2, p0, p1, p2, outp, cx0, a0, clampL, storeok);
    vstep<3, true,  true,  false, true>(S, y0 + 3, p0, p1, p2, outp, cx0, a0, clampL, storeok);
    // steady: k=8..RB+3, refill on (RB=8: one 4-step block)
    #pragma unroll 1
    for (int kb = 8; kb < RB + 4; kb += 4) {
        int yL = y0 - 4 + kb;
        vstep<0, true, true, true, true>(S, yL + 0, p0, p1, p2, outp, cx0, a0, clampL, storeok);
        vstep<1, true, true, true, true>(S, yL + 1, p0, p1, p2, outp, cx0, a0, clampL, storeok);
        vstep<2, true, true, true, true>(S, yL + 2, p0, p1, p2, outp, cx0, a0, clampL, storeok);
        vstep<3, true, true, true, true>(S, yL + 3, p0, p1, p2, outp, cx0, a0, clampL, storeok);
    }
    // tail: last 4 steps, no refill
    {
        int yL = y0 + RB;
        vstep<0, true, true, true, false>(S, yL + 0, p0, p1, p2, outp, cx0, a0, clampL, storeok);
        vstep<1, true, true, true, false>(S, yL + 1, p0, p1, p2, outp, cx0, a0, clampL, storeok);
        vstep<2, true, true, true, false>(S, yL + 2, p0, p1, p2, outp, cx0, a0, clampL, storeok);
        vstep<3, true, true, true, false>(S, yL + 3, p0, p1, p2, outp, cx0, a0, clampL, storeok);
    }
}

// ---------------- scalar path (strip C only: right edge, 64 cols) ------------
__device__ __forceinline__ void run_band_sc(const float* __restrict__ p0,
                                            const float* __restrict__ p1,
                                            const float* __restrict__ p2,
                                            float* __restrict__ outp,
                                            int y0, int c0, int lane) {
    const float w0 = 0.05448868f, w1 = 0.24420134f, w2 = 0.40261995f;
    const int cx = c0 + lane;
    const int rx = reflect_i(cx, IMW);
    const int ixm = ((cx - 1 < 0) ? 0 : (cx - 1 >= IMW ? IMW - 1 : cx - 1)) - c0;
    const int ixp = ((cx + 1 < 0) ? 0 : (cx + 1 >= IMW ? IMW - 1 : cx + 1)) - c0;
    const bool storeok = (lane >= 4) && (lane < 60) && ((unsigned)cx < (unsigned)IMW);

    float h0 = 0, h1 = 0, h2 = 0, h3 = 0;
    float b_1 = 0, b_0 = 0, bl_1 = 0, bl_0 = 0, br_1 = 0, br_0 = 0;
    float m_1 = 0, m_0 = 0, ml_1 = 0, ml_0 = 0, mr_1 = 0, mr_0 = 0;
    float gxp = 0, gyp = 0;

    float rr[4], gg[4], bb[4];
    #pragma unroll
    for (int k = 0; k < 4; ++k) {
        int yo = reflect_row(y0 - 4 + k) * IMW + rx;
        rr[k] = p0[yo]; gg[k] = p1[yo]; bb[k] = p2[yo];
    }

    #pragma unroll
    for (int k = 0; k < RB + 8; ++k) {
        const int yL = y0 - 4 + k;
        const int sl = k & 3;
        float gray = 0.1495f * rr[sl] + 0.2935f * gg[sl] + 0.057f * bb[sl];
        if (k + 4 < RB + 8) {
            int yo = reflect_row(yL + 4) * IMW + rx;
            rr[sl] = p0[yo]; gg[sl] = p1[yo]; bb[sl] = p2[yo];
        }
        float gm1 = dpp_shr1(gray);
        float gm2 = dpp_shr1(gm1);
        float gp1 = dpp_shl1(gray);
        float gp2 = dpp_shl1(gp1);
        float hnew = w0 * (gm2 + gp2) + w1 * (gm1 + gp1) + w2 * gray;

        float bnew = 0, blnew = 0, brnew = 0;
        if (k >= 4) {
            bnew = w0 * (h0 + hnew) + w1 * (h1 + h3) + w2 * h2;
            blnew = __shfl(bnew, ixm); brnew = __shfl(bnew, ixp);
        }

        float mnew = 0, mlnew = 0, mrnew = 0, gx = 0, gy = 0;
        if (k >= 6) {
            int u = yL - 3;
            float ta = b_1, tla = bl_1, tra = br_1;
            float tb = bnew, tlb = blnew, trb = brnew;
            if (u == 0)       { ta = b_0; tla = bl_0; tra = br_0; }
            if (u == IMH - 1) { tb = b_0; tlb = bl_0; trb = br_0; }
            gx = (tra - tla) + 2.0f * (br_0 - bl_0) + (trb - tlb);
            gy = (tlb - tla) + 2.0f * (tb - ta) + (trb - tra);
            mnew = __builtin_amdgcn_sqrtf(gx * gx + gy * gy + 1e-6f);
            if ((unsigned)cx >= (unsigned)IMW) mnew = 0.0f;
            mlnew = dpp_shr1(mnew);
            mrnew = dpp_shl1(mnew);
        }

        if (k >= 8) {
            int s = yL - 4;
            float pm = m_1, pml = ml_1, pmr = mr_1;
            float nm = mnew, nml = mlnew, nmr = mrnew;
            if (s == 0)       { pm = 0; pml = 0; pmr = 0; }
            if (s == IMH - 1) { nm = 0; nml = 0; nmr = 0; }
            float ax = fabsf(gxp), ay = fabsf(gyp);
            bool ew = (ay <= 0.41421356237f * ax);
            bool ns = (ay >= 2.41421356237f * ax);
            bool d1 = (gxp * gyp > 0.0f);
            float n1 = ew ? mr_0 : (ns ? nm : (d1 ? pmr : nmr));
            float n2 = ew ? ml_0 : (ns ? pm : (d1 ? nml : pml));
            float mag = m_0;
            float o = (mag > n1 && mag > n2) ? mag : 0.0f;
            if (storeok)
                __builtin_nontemporal_store(o, &outp[(size_t)s * IMW + cx]);
        }

        h0 = h1; h1 = h2; h2 = h3; h3 = hnew;
        b_1 = b_0;  b_0 = bnew;
        bl_1 = bl_0; bl_0 = blnew;
        br_1 = br_0; br_0 = brnew;
        m_1 = m_0;  m_0 = mnew;
        ml_1 = ml_0; ml_0 = mlnew;
        mr_1 = mr_0; mr_0 = mrnew;
        gxp = gx; gyp = gy;
    }
}

__global__ __launch_bounds__(256, 2)
void canny_stream(const float* __restrict__ data, float* __restrict__ out) {
    const int lane = threadIdx.x & 63;
    // XCD-aware swizzle: blocks with equal blockIdx%8 -> one XCD;
    // each XCD owns 2 batches (6MB) walked band-sequentially for L2 halo hits.
    // waves: (bat) x (band 0..63) x (strip 0..2); 3072 waves = 768 blocks.
    const int xcd = blockIdx.x & 7;
    const int seq = blockIdx.x >> 3;               // 0..95
    const int lw  = seq * 4 + (threadIdx.x >> 6);  // 0..383 within XCD
    const int strip = lw % 3;
    const int t = lw / 3;                          // 0..127
    const int band = t & (NBAND - 1);
    const int bat = (xcd << 1) | (t >> 6);
    const int y0 = band * RB;

    const size_t plane = (size_t)(IMH * IMW);
    const float* p0 = data + (size_t)bat * 3 * plane;
    const float* p1 = p0 + plane;
    const float* p2 = p1 + plane;
    float* outp = out + (size_t)bat * plane;

    if (strip == 2) {
        run_band_sc(p0, p1, p2, outp, y0, 488, lane);          // out 492..511
    } else if (strip == 0) {
        run_band_v4(p0, p1, p2, outp, y0, -4, lane, true);     // out 0..247
    } else {
        run_band_v4(p0, p1, p2, outp, y0, 244, lane, false);   // out 248..491
    }
}

extern "C" void kernel_launch(void* const* d_in, const int* in_sizes, int n_in,
                              void* d_out, int out_size, void* d_ws, size_t ws_size,
                              hipStream_t stream) {
    const float* data = (const float*)d_in[0];
    float* out = (float*)d_out;
    int B = in_sizes[0] / (3 * IMH * IMW);       // 16
    int blocks = (B * NBAND * 3) / 4;            // 768 blocks, 3072 waves
    canny_stream<<<blocks, dim3(256, 1, 1), 0, stream>>>(data, out);
}